// Round 4
// baseline (80.388 us; speedup 1.0000x reference)
//
#include <hip/hip_runtime.h>
#include <hip/hip_bf16.h>
#include <math.h>

// Problem constants (fixed by setup_inputs in the reference):
//   features: [B=2, C=512, H=50, W=64] float32
//   roiss:    [B=2, N=128, 4]          float32  (x1,y1,x2,y2 pixel coords)
//   out:      [B, N, C]                float32
//
// Region-size bound: box w,h <= 84 px; feature cell = 16 px both axes
// (1024/64, 800/50) -> region span <= ceil(84/16)+1 = 7 cells per axis.
// An 8x8 lane tile therefore covers any region in ONE masked load per
// (roi, channel); the tile loops below still handle larger spans correctly.
#define IMG_W_F 1024.0f
#define IMG_H_F 800.0f

__global__ __launch_bounds__(256) void roipool_fused(
    const float* __restrict__ feat,   // [B, C, H, W]
    const float* __restrict__ rois,   // [B, N, 4]
    float* __restrict__ out,          // [B, N, C]
    int C, int H, int W, int N)
{
    const int bn = blockIdx.x;        // b * N + n
    const int b  = bn / N;

    // ---- box math: replicate reference fp32 op order exactly (R1-verified) ----
    const float* roi = rois + (size_t)bn * 4;
    const float rx1 = roi[0], ry1 = roi[1], rx2 = roi[2], ry2 = roi[3];

    int x1 = (int)floorf(rx1 / IMG_W_F * (float)W);
    int y1 = (int)floorf(ry1 / IMG_H_F * (float)H);
    int x2 = (int)ceilf (rx2 / IMG_W_F * (float)W);
    int y2 = (int)ceilf (ry2 / IMG_H_F * (float)H);
    x1 = max(x1, 0);
    y1 = max(y1, 0);
    x2 = max(x2, 0);
    y2 = max(y2, 0);
    if (x1 == 0 && x2 == 0) x2 = 1;     // degenerate-box fixes, reference order
    if (y1 == 0 && y2 == 0) y2 = 1;
    if (x1 >= W) x1 = W - 1;
    if (y1 >= H) y1 = H - 1;
    const int ye = min(y2, H);
    const int xe = min(x2, W);

    // ---- lane -> (dy, dx) in an 8x8 region tile ----
    const int lane = threadIdx.x & 63;
    const int wv   = threadIdx.x >> 6;               // wave id 0..3
    const int c0   = blockIdx.y * 128 + wv * 32;     // 32 channels per wave
    const int dy   = lane >> 3;
    const int dx   = lane & 7;

    const float* fb = feat + (size_t)b * C * H * W;

    float res = 0.0f;                                // filled via lane-select below
#pragma unroll 8
    for (int i = 0; i < 32; ++i) {
        const int c = c0 + i;
        const float* fc = fb + (size_t)c * (H * W);

        // Gather this lane's region cell(s); lanes outside the span do zero
        // iterations and keep -inf (they never win the max).
        float m = -INFINITY;
        for (int ty = y1 + dy; ty < ye; ty += 8) {
            const float* fr = fc + ty * W;
            for (int tx = x1 + dx; tx < xe; tx += 8) {
                m = fmaxf(m, fr[tx]);
            }
        }

        // Butterfly max across the full 64-lane wave.
#pragma unroll
        for (int off = 32; off > 0; off >>= 1) {
            m = fmaxf(m, __shfl_xor(m, off, 64));
        }

        // Park channel i's result in lane i for a coalesced final store.
        if (lane == i) res = m;
    }

    if (lane < 32) {
        out[(size_t)bn * C + c0 + lane] = res;
    }
}

extern "C" void kernel_launch(void* const* d_in, const int* in_sizes, int n_in,
                              void* d_out, int out_size, void* d_ws, size_t ws_size,
                              hipStream_t stream) {
    const int B = 2, C = 512, H = 50, W = 64, N = 128;

    const float* feat = (const float*)d_in[0];
    const float* rois = (const float*)d_in[1];
    float* out = (float*)d_out;

    // grid: 256 ROIs x 4 channel-groups (128 ch each); block: 4 waves.
    dim3 grid(B * N, C / 128);
    dim3 block(256);
    roipool_fused<<<grid, block, 0, stream>>>(feat, rois, out, C, H, W, N);
}

// Round 5
// 74.769 us; speedup vs baseline: 1.0752x; 1.0752x over previous
//
#include <hip/hip_runtime.h>
#include <hip/hip_bf16.h>
#include <math.h>

// Problem constants (fixed by setup_inputs in the reference):
//   features: [B=2, C=512, H=50, W=64] float32
//   roiss:    [B=2, N=128, 4]          float32  (x1,y1,x2,y2 pixel coords)
//   out:      [B, N, C]                float32
#define IMG_W_F 1024.0f
#define IMG_H_F 800.0f

// One block = (one ROI, 128 channels); thread = one channel.
// grid = (B*N, C/128) = 1024 blocks, 128 threads (2 waves) each
//   -> ~4 blocks/CU = 8 waves/CU (2x R1's latency hiding) and 4x finer
//      granularity for balancing the ~4x per-ROI region-size variance.
__global__ __launch_bounds__(128) void roipool_kernel(
    const float* __restrict__ feat,   // [B, C, H, W]
    const float* __restrict__ rois,   // [B, N, 4]
    float* __restrict__ out,          // [B, N, C]
    int C, int H, int W, int N)
{
    const int bn = blockIdx.x;            // b * N + n
    const int b  = bn / N;

    // ---- box math: replicate reference fp32 op order exactly (R1-verified) ----
    const float* roi = rois + (size_t)bn * 4;
    const float rx1 = roi[0], ry1 = roi[1], rx2 = roi[2], ry2 = roi[3];

    int x1 = (int)floorf(rx1 / IMG_W_F * (float)W);
    int y1 = (int)floorf(ry1 / IMG_H_F * (float)H);
    int x2 = (int)ceilf (rx2 / IMG_W_F * (float)W);
    int y2 = (int)ceilf (ry2 / IMG_H_F * (float)H);
    x1 = max(x1, 0);
    y1 = max(y1, 0);
    x2 = max(x2, 0);
    y2 = max(y2, 0);
    if (x1 == 0 && x2 == 0) x2 = 1;     // degenerate-box fixes, reference order
    if (y1 == 0 && y2 == 0) y2 = 1;
    if (x1 >= W) x1 = W - 1;
    if (y1 >= H) y1 = H - 1;
    const int ye = min(y2, H);
    const int xe = min(x2, W);

    const int c = blockIdx.y * 128 + threadIdx.x;   // one channel per thread

    const float* fc = feat + ((size_t)b * C + c) * (H * W);
    float m = -INFINITY;
    for (int y = y1; y < ye; ++y) {
        const float* fr = fc + y * W;
        for (int x = x1; x < xe; ++x) {
            m = fmaxf(m, fr[x]);
        }
    }
    out[(size_t)bn * C + c] = m;        // coalesced 128-wide store
}

extern "C" void kernel_launch(void* const* d_in, const int* in_sizes, int n_in,
                              void* d_out, int out_size, void* d_ws, size_t ws_size,
                              hipStream_t stream) {
    const int B = 2, C = 512, H = 50, W = 64, N = 128;

    const float* feat = (const float*)d_in[0];
    const float* rois = (const float*)d_in[1];
    float* out = (float*)d_out;

    dim3 grid(B * N, C / 128);   // 256 x 4 = 1024 blocks
    dim3 block(128);             // thread = one channel
    roipool_kernel<<<grid, block, 0, stream>>>(feat, rois, out, C, H, W, N);
}